// Round 1
// baseline (943.382 us; speedup 1.0000x reference)
//
#include <hip/hip_runtime.h>
#include <hip/hip_bf16.h>

#define T_LEN 124
#define C_LEN 144
#define H_LEN 36

// Dynamic LDS layout (byte offsets):
//   xs  @ 0      : f32 [124][148] = 73408 B  (phases 1-2; reused as wei f32 [124][132] = 65472 B)
//   Wt  @ 73408  : bf16[108][152] = 32832 B  (phases 1-2; reused as outstage f32 [124][36] = 17856 B)
//   ks  @ 106240 : f32 [124][36]  = 17856 B
//   qs  @ 124096 : f32 [124][36]  = 17856 B
//   vst @ 141952 : f32 [36][132]  = 19008 B  (v transposed: vst[h][t])
//   total 160960 B  (<= 163840)
#define LDS_BYTES 160960

__device__ __forceinline__ void bf2f(unsigned u, float& lo, float& hi) {
    union U { unsigned u; float f; } a, b;
    a.u = u << 16;          // low bf16 -> f32
    b.u = u & 0xFFFF0000u;  // high bf16 -> f32
    lo = a.f; hi = b.f;
}

__global__ __launch_bounds__(256, 1)
void head_fused(const float* __restrict__ x,
                const float* __restrict__ Wk,
                const float* __restrict__ Wq,
                const float* __restrict__ Wv,
                float* __restrict__ out)
{
    extern __shared__ char lds[];
    float*          xs  = (float*)(lds);
    __hip_bfloat16* Wt  = (__hip_bfloat16*)(lds + 73408);
    float*          ks  = (float*)(lds + 106240);
    float*          qs  = (float*)(lds + 124096);
    float*          vst = (float*)(lds + 141952);
    float*          wei = (float*)(lds);          // overlays dead xs after phase 2
    float*          ost = (float*)(lds + 73408);  // overlays dead Wt after phase 2

    const int tid = threadIdx.x;
    const int b   = blockIdx.x;
    const float* xg = x + (size_t)b * (T_LEN * C_LEN);

    // ---------------- Phase 1: stage x (f32) and W (bf16, transposed) ----------------
    {
        const float4* xg4 = (const float4*)xg;
        for (int i = tid; i < T_LEN * (C_LEN / 4); i += 256) {
            const int t = i / (C_LEN / 4), c4 = i % (C_LEN / 4);
            *(float4*)(xs + t * 148 + c4 * 4) = xg4[i];
        }
        const float* Ws[3] = {Wk, Wq, Wv};
        #pragma unroll
        for (int m = 0; m < 3; ++m) {
            const float4* wg4 = (const float4*)Ws[m];
            for (int i = tid; i < C_LEN * (H_LEN / 4); i += 256) {
                const int c = i / (H_LEN / 4), hh = (i % (H_LEN / 4)) * 4;
                const float4 v = wg4[i];
                Wt[(m * H_LEN + hh + 0) * 152 + c] = __float2bfloat16(v.x);
                Wt[(m * H_LEN + hh + 1) * 152 + c] = __float2bfloat16(v.y);
                Wt[(m * H_LEN + hh + 2) * 152 + c] = __float2bfloat16(v.z);
                Wt[(m * H_LEN + hh + 3) * 152 + c] = __float2bfloat16(v.w);
            }
        }
    }
    __syncthreads();

    // ---------------- Phase 2: [k|q|v] = x @ [Wk|Wq|Wv], combined h = 0..107 ----------------
    {
        const int ty = tid >> 4, tx = tid & 15;
        float acc[8][7];
        #pragma unroll
        for (int j = 0; j < 8; ++j)
            #pragma unroll
            for (int k = 0; k < 7; ++k) acc[j][k] = 0.f;

        for (int cc = 0; cc < C_LEN; cc += 8) {
            float wf[7][8];
            #pragma unroll
            for (int k = 0; k < 7; ++k) {
                const int h = tx + 16 * k;
                if (h < 108) {
                    const uint4 wv = *(const uint4*)(Wt + h * 152 + cc);
                    bf2f(wv.x, wf[k][0], wf[k][1]);
                    bf2f(wv.y, wf[k][2], wf[k][3]);
                    bf2f(wv.z, wf[k][4], wf[k][5]);
                    bf2f(wv.w, wf[k][6], wf[k][7]);
                } else {
                    #pragma unroll
                    for (int i = 0; i < 8; ++i) wf[k][i] = 0.f;
                }
            }
            #pragma unroll
            for (int j = 0; j < 8; ++j) {
                // rows t >= 124 read in-bounds LDS garbage; their stores are guarded
                const float4 xa = *(const float4*)(xs + (ty * 8 + j) * 148 + cc);
                const float4 xb = *(const float4*)(xs + (ty * 8 + j) * 148 + cc + 4);
                const float xr[8] = {xa.x, xa.y, xa.z, xa.w, xb.x, xb.y, xb.z, xb.w};
                #pragma unroll
                for (int k = 0; k < 7; ++k)
                    #pragma unroll
                    for (int i = 0; i < 8; ++i)
                        acc[j][k] = fmaf(xr[i], wf[k][i], acc[j][k]);
            }
        }
        #pragma unroll
        for (int j = 0; j < 8; ++j) {
            const int t = ty * 8 + j;
            if (t < T_LEN) {
                #pragma unroll
                for (int k = 0; k < 7; ++k) {
                    const int h = tx + 16 * k;
                    if (h < 36)       ks[t * 36 + h]           = acc[j][k];
                    else if (h < 72)  qs[t * 36 + (h - 36)]    = acc[j][k];
                    else if (h < 108) vst[(h - 72) * 132 + t]  = acc[j][k];
                }
            }
        }
    }
    __syncthreads();

    // ---------------- Phase 3: scores (k[t]·q[s]/12) + causal softmax -> wei ----------------
    {
        const int wid  = tid >> 6;   // wave 0..3, owns rows t = 4j + wid
        const int lane = tid & 63;
        float q1[36], q2[36];
        {
            const float4* qp = (const float4*)(qs + lane * 36);
            #pragma unroll
            for (int i = 0; i < 9; ++i) {
                const float4 v = qp[i];
                q1[4*i+0] = v.x; q1[4*i+1] = v.y; q1[4*i+2] = v.z; q1[4*i+3] = v.w;
            }
            if (lane + 64 < T_LEN) {
                const float4* qp2 = (const float4*)(qs + (lane + 64) * 36);
                #pragma unroll
                for (int i = 0; i < 9; ++i) {
                    const float4 v = qp2[i];
                    q2[4*i+0] = v.x; q2[4*i+1] = v.y; q2[4*i+2] = v.z; q2[4*i+3] = v.w;
                }
            } else {
                #pragma unroll
                for (int h = 0; h < 36; ++h) q2[h] = 0.f;
            }
        }
        const float scale = 1.0f / 12.0f;  // C^-0.5, C = 144
        for (int j = 0; j < 31; ++j) {
            const int t = 4 * j + wid;
            float kv[36];
            const float4* kp = (const float4*)(ks + t * 36);
            #pragma unroll
            for (int i = 0; i < 9; ++i) {
                const float4 v = kp[i];
                kv[4*i+0] = v.x; kv[4*i+1] = v.y; kv[4*i+2] = v.z; kv[4*i+3] = v.w;
            }
            float d1 = 0.f, d2 = 0.f;
            #pragma unroll
            for (int h = 0; h < 36; ++h) {
                d1 = fmaf(kv[h], q1[h], d1);
                d2 = fmaf(kv[h], q2[h], d2);
            }
            const float sc1 = d1 * scale, sc2 = d2 * scale;
            const bool v1 = (lane <= t), v2 = (lane + 64 <= t);
            float ml = v1 ? sc1 : -__builtin_inff();
            ml = fmaxf(ml, v2 ? sc2 : -__builtin_inff());
            #pragma unroll
            for (int o = 32; o > 0; o >>= 1) ml = fmaxf(ml, __shfl_xor(ml, o));
            const float e1 = v1 ? __expf(sc1 - ml) : 0.f;
            const float e2 = v2 ? __expf(sc2 - ml) : 0.f;
            float sl = e1 + e2;
            #pragma unroll
            for (int o = 32; o > 0; o >>= 1) sl += __shfl_xor(sl, o);
            const float r = __builtin_amdgcn_rcpf(sl);
            wei[t * 132 + lane]      = e1 * r;   // cols 124..127 get 0 (v2 false)
            wei[t * 132 + 64 + lane] = e2 * r;
        }
    }
    __syncthreads();

    // ---------------- Phase 4: out[t][h] = sum_s wei[t][s] * v[s][h] ----------------
    {
        const int ty = tid >> 3;  // 0..31 -> 4 rows each
        const int tx = tid & 7;   // 0..7  -> 5 h-slots (36/8)
        float acc[4][5];
        #pragma unroll
        for (int j = 0; j < 4; ++j)
            #pragma unroll
            for (int k = 0; k < 5; ++k) acc[j][k] = 0.f;

        for (int ss = 0; ss < T_LEN; ss += 4) {   // 124 = 31*4, exact
            float wv[5][4];
            #pragma unroll
            for (int k = 0; k < 5; ++k) {
                const int h = tx + 8 * k;
                if (h < 36) {
                    const float4 v = *(const float4*)(vst + h * 132 + ss);
                    wv[k][0] = v.x; wv[k][1] = v.y; wv[k][2] = v.z; wv[k][3] = v.w;
                } else {
                    #pragma unroll
                    for (int i = 0; i < 4; ++i) wv[k][i] = 0.f;
                }
            }
            #pragma unroll
            for (int j = 0; j < 4; ++j) {
                const float4 wr = *(const float4*)(wei + (ty * 4 + j) * 132 + ss);
                const float wrr[4] = {wr.x, wr.y, wr.z, wr.w};
                #pragma unroll
                for (int k = 0; k < 5; ++k)
                    #pragma unroll
                    for (int i = 0; i < 4; ++i)
                        acc[j][k] = fmaf(wrr[i], wv[k][i], acc[j][k]);
            }
        }
        #pragma unroll
        for (int j = 0; j < 4; ++j) {
            const int t = ty * 4 + j;
            if (t < T_LEN) {
                #pragma unroll
                for (int k = 0; k < 5; ++k) {
                    const int h = tx + 8 * k;
                    if (h < 36) ost[t * 36 + h] = acc[j][k];
                }
            }
        }
    }
    __syncthreads();

    // ---------------- Phase 5: coalesced store ----------------
    {
        float4* og = (float4*)(out + (size_t)b * (T_LEN * H_LEN));
        const float4* os = (const float4*)ost;
        for (int i = tid; i < (T_LEN * H_LEN) / 4; i += 256) og[i] = os[i];
    }
}

extern "C" void kernel_launch(void* const* d_in, const int* in_sizes, int n_in,
                              void* d_out, int out_size, void* d_ws, size_t ws_size,
                              hipStream_t stream) {
    const float* x  = (const float*)d_in[0];
    const float* Wk = (const float*)d_in[1];
    const float* Wq = (const float*)d_in[2];
    const float* Wv = (const float*)d_in[3];
    float* out = (float*)d_out;
    const int B = in_sizes[0] / (T_LEN * C_LEN);   // 4096
    hipFuncSetAttribute((const void*)head_fused,
                        hipFuncAttributeMaxDynamicSharedMemorySize, LDS_BYTES);
    head_fused<<<dim3(B), dim3(256), LDS_BYTES, stream>>>(x, Wk, Wq, Wv, out);
}

// Round 2
// 151.555 us; speedup vs baseline: 6.2247x; 6.2247x over previous
//
#include <hip/hip_runtime.h>

#define TL 124
#define CL 144
#define HL 36

typedef unsigned short u16;
typedef short bf16x8 __attribute__((ext_vector_type(8)));
typedef float f32x4  __attribute__((ext_vector_type(4)));

// LDS layout (bytes):
//   k   @ 0      : bf16 [124][72]   = 17856   (row stride 72 elems = 144 B)
//   q   @ 17856  : bf16 [124][72]   = 17856
//   wei @ 0      : bf16 [128][136]  = 34816   (overlays dead k+q after scores)
//   vT  @ 35712  : bf16 [48][136]   = 13056   (v transposed: vT[h][t])
#define K_STRIDE 72
#define W_STRIDE 136
#define V_STRIDE 136
#define Q_OFF    17856
#define VT_OFF   35712
#define LDS_BYTES 48768

// ws image: bf16 [5 kchunks][144 h_padded][40 kcols]; h_padded = 48*sec + hh,
// sec 0/1/2 = Wk/Wq/Wv, hh<36 valid else 0; kcol = 32*chunk + kk, kk<32 & <144 valid.
#define WS_ELEMS (5 * 144 * 40)

__device__ __forceinline__ u16 f2b(float f) {
    union { float f; unsigned u; } c; c.f = f;
    unsigned u = c.u;
    u += 0x7FFFu + ((u >> 16) & 1u);     // round-to-nearest-even
    return (u16)(u >> 16);
}
__device__ __forceinline__ float b2f(u16 h) {
    union { unsigned u; float f; } c; c.u = ((unsigned)h) << 16; return c.f;
}

__global__ void prepack_w(const float* __restrict__ Wk, const float* __restrict__ Wq,
                          const float* __restrict__ Wv, u16* __restrict__ wt) {
    int i = blockIdx.x * 256 + threadIdx.x;
    if (i >= WS_ELEMS) return;
    int kk = i % 40;
    int hp = (i / 40) % 144;
    int ck = i / (40 * 144);
    int sec = hp / 48, hh = hp % 48;
    int kc = ck * 32 + kk;
    float v = 0.f;
    if (kk < 32 && kc < CL && hh < HL) {
        const float* W = (sec == 0) ? Wk : (sec == 1) ? Wq : Wv;
        v = W[kc * HL + hh];
    }
    wt[i] = f2b(v);
}

template<int USEWS>
__global__ __launch_bounds__(256, 3)
void head_mfma(const float* __restrict__ x,
               const float* __restrict__ Wk, const float* __restrict__ Wq,
               const float* __restrict__ Wv,
               const u16* __restrict__ wt,
               float* __restrict__ out)
{
    extern __shared__ char lds[];
    u16* ks_ = (u16*)(lds);
    u16* qs_ = (u16*)(lds + Q_OFF);
    u16* ws_ = (u16*)(lds);            // wei overlays k,q (k,q dead by then)
    u16* vs_ = (u16*)(lds + VT_OFF);

    const int tid = threadIdx.x;
    const int wv  = tid >> 6;          // wave 0..3
    const int l   = tid & 63;
    const int lo  = l & 15;
    const int hi  = l >> 4;
    const int b   = blockIdx.x;
    const float* xb = x + (size_t)b * (TL * CL);

    // phase -1: zero k/q cols 48..63 (read by scores k-step 1, never written)
    for (int idx = tid; idx < 496; idx += 256) {
        int a = idx / 248, j = idx % 248;
        int rr = j >> 1, half = j & 1;
        u16* p = (a ? qs_ : ks_) + rr * K_STRIDE + 48 + half * 8;
        *(uint4*)p = make_uint4(0u, 0u, 0u, 0u);
    }

    // ---------------- phase K: [k|q|v] = x @ [Wk|Wq|Wv] (MFMA, no barriers) ----------------
    const int mt0 = wv * 2;            // this wave's 2 M-tiles
    f32x4 acc[2][9];
    #pragma unroll
    for (int m = 0; m < 2; ++m)
        #pragma unroll
        for (int n = 0; n < 9; ++n) acc[m][n] = (f32x4){0.f, 0.f, 0.f, 0.f};

    int tr[2];
    tr[0] = 16 * mt0 + lo;      if (tr[0] > TL - 1) tr[0] = TL - 1;   // clamp (rows >=124 discarded)
    tr[1] = 16 * mt0 + 16 + lo; if (tr[1] > TL - 1) tr[1] = TL - 1;

    #pragma unroll
    for (int ksep = 0; ksep < 5; ++ksep) {
        bf16x8 ah[2], al[2];
        #pragma unroll
        for (int m = 0; m < 2; ++m) {
            if (ksep < 4 || hi < 2) {   // k-cols 128..143 only for hi<2; rest zero-pad
                const float* px = xb + tr[m] * CL + ksep * 32 + hi * 8;
                float4 u = *(const float4*)px;
                float4 v = *(const float4*)(px + 4);
                float f[8] = {u.x, u.y, u.z, u.w, v.x, v.y, v.z, v.w};
                #pragma unroll
                for (int j = 0; j < 8; ++j) {
                    u16 hb = f2b(f[j]);
                    ah[m][j] = (short)hb;
                    al[m][j] = (short)f2b(f[j] - b2f(hb));   // split-bf16 residual
                }
            } else {
                ah[m] = (bf16x8){0,0,0,0,0,0,0,0};
                al[m] = (bf16x8){0,0,0,0,0,0,0,0};
            }
        }
        #pragma unroll
        for (int nt = 0; nt < 9; ++nt) {
            bf16x8 bfr;
            if (USEWS) {
                bfr = *(const bf16x8*)(wt + (size_t)(ksep * 144 + 16 * nt + lo) * 40 + hi * 8);
            } else {
                int hp = 16 * nt + lo;
                int sec = hp / 48, hh = hp % 48;
                const float* W = (sec == 0) ? Wk : (sec == 1) ? Wq : Wv;
                if (hh < HL && (ksep < 4 || hi < 2)) {
                    #pragma unroll
                    for (int j = 0; j < 8; ++j)
                        bfr[j] = (short)f2b(W[(ksep * 32 + hi * 8 + j) * HL + hh]);
                } else bfr = (bf16x8){0,0,0,0,0,0,0,0};
            }
            #pragma unroll
            for (int m = 0; m < 2; ++m) {
                acc[m][nt] = __builtin_amdgcn_mfma_f32_16x16x32_bf16(ah[m], bfr, acc[m][nt], 0, 0, 0);
                acc[m][nt] = __builtin_amdgcn_mfma_f32_16x16x32_bf16(al[m], bfr, acc[m][nt], 0, 0, 0);
            }
        }
    }

    // write k,q (bf16, b16 scatter) and vT (b64 packed); D layout: row=(hi*4+r), col=lo
    #pragma unroll
    for (int m = 0; m < 2; ++m) {
        const int tb = 16 * (mt0 + m) + hi * 4;
        #pragma unroll
        for (int nt = 0; nt < 9; ++nt) {
            if (nt < 6) {
                u16* dst = (nt < 3) ? ks_ : qs_;
                const int h0 = (nt < 3) ? 16 * nt : 16 * (nt - 3);
                #pragma unroll
                for (int r = 0; r < 4; ++r) {
                    const int t = tb + r;
                    if (t < TL) dst[t * K_STRIDE + h0 + lo] = f2b(acc[m][nt][r]);
                }
            } else {
                const int hv = 16 * (nt - 6) + lo;
                union { u16 s[4]; uint2 d; } pk;
                #pragma unroll
                for (int r = 0; r < 4; ++r) pk.s[r] = f2b(acc[m][nt][r]);
                *(uint2*)(vs_ + hv * V_STRIDE + tb) = pk.d;   // rows >=124 land in vT cols 124..127: finite, wei=0 there
            }
        }
    }
    __syncthreads();

    // ---------------- phase S: scores = k @ q^T (MFMA), then causal softmax ----------------
    f32x4 sa[2][8];
    #pragma unroll
    for (int m = 0; m < 2; ++m)
        #pragma unroll
        for (int n = 0; n < 8; ++n) sa[m][n] = (f32x4){0.f, 0.f, 0.f, 0.f};

    #pragma unroll
    for (int ksep = 0; ksep < 2; ++ksep) {
        bf16x8 af[2];
        #pragma unroll
        for (int m = 0; m < 2; ++m)
            af[m] = *(const bf16x8*)(ks_ + (16 * (mt0 + m) + lo) * K_STRIDE + ksep * 32 + hi * 8);
        #pragma unroll
        for (int nt = 0; nt < 8; ++nt) {
            bf16x8 bq = *(const bf16x8*)(qs_ + (16 * nt + lo) * K_STRIDE + ksep * 32 + hi * 8);
            #pragma unroll
            for (int m = 0; m < 2; ++m)
                sa[m][nt] = __builtin_amdgcn_mfma_f32_16x16x32_bf16(af[m], bq, sa[m][nt], 0, 0, 0);
        }
    }
    __syncthreads();   // all k/q reads done before wei overlays them

    const float scl = 1.0f / 12.0f;    // C^-0.5, C = 144 (faithful to reference)
    #pragma unroll
    for (int m = 0; m < 2; ++m) {
        #pragma unroll
        for (int r = 0; r < 4; ++r) {
            const int t = 16 * (mt0 + m) + hi * 4 + r;
            float v8[8];
            float mx = -__builtin_inff();
            #pragma unroll
            for (int nt = 0; nt < 8; ++nt) {
                const float sc = sa[m][nt][r] * scl;
                v8[nt] = (16 * nt + lo <= t) ? sc : -__builtin_inff();
                mx = fmaxf(mx, v8[nt]);
            }
            mx = fmaxf(mx, __shfl_xor(mx, 1));
            mx = fmaxf(mx, __shfl_xor(mx, 2));
            mx = fmaxf(mx, __shfl_xor(mx, 4));
            mx = fmaxf(mx, __shfl_xor(mx, 8));
            float e8[8], sum = 0.f;
            #pragma unroll
            for (int nt = 0; nt < 8; ++nt) { e8[nt] = __expf(v8[nt] - mx); sum += e8[nt]; }
            sum += __shfl_xor(sum, 1);
            sum += __shfl_xor(sum, 2);
            sum += __shfl_xor(sum, 4);
            sum += __shfl_xor(sum, 8);
            const float rs = __builtin_amdgcn_rcpf(sum);
            #pragma unroll
            for (int nt = 0; nt < 8; ++nt)
                ws_[t * W_STRIDE + 16 * nt + lo] = f2b(e8[nt] * rs);   // cols 124..127 always masked -> 0
        }
    }
    __syncthreads();

    // ---------------- phase P: out = wei @ v (MFMA), direct global store ----------------
    f32x4 pa[2][3];
    #pragma unroll
    for (int m = 0; m < 2; ++m)
        #pragma unroll
        for (int n = 0; n < 3; ++n) pa[m][n] = (f32x4){0.f, 0.f, 0.f, 0.f};

    #pragma unroll
    for (int ksep = 0; ksep < 4; ++ksep) {
        bf16x8 af[2];
        #pragma unroll
        for (int m = 0; m < 2; ++m)
            af[m] = *(const bf16x8*)(ws_ + (16 * (mt0 + m) + lo) * W_STRIDE + ksep * 32 + hi * 8);
        #pragma unroll
        for (int nt = 0; nt < 3; ++nt) {
            bf16x8 bv = *(const bf16x8*)(vs_ + (16 * nt + lo) * V_STRIDE + ksep * 32 + hi * 8);
            #pragma unroll
            for (int m = 0; m < 2; ++m)
                pa[m][nt] = __builtin_amdgcn_mfma_f32_16x16x32_bf16(af[m], bv, pa[m][nt], 0, 0, 0);
        }
    }
    float* ob = out + (size_t)b * (TL * HL);
    #pragma unroll
    for (int m = 0; m < 2; ++m) {
        #pragma unroll
        for (int nt = 0; nt < 3; ++nt) {
            #pragma unroll
            for (int r = 0; r < 4; ++r) {
                const int t = 16 * (mt0 + m) + hi * 4 + r;
                const int h = 16 * nt + lo;
                if (t < TL && h < HL) ob[t * HL + h] = pa[m][nt][r];
            }
        }
    }
}

extern "C" void kernel_launch(void* const* d_in, const int* in_sizes, int n_in,
                              void* d_out, int out_size, void* d_ws, size_t ws_size,
                              hipStream_t stream) {
    const float* x  = (const float*)d_in[0];
    const float* Wk = (const float*)d_in[1];
    const float* Wq = (const float*)d_in[2];
    const float* Wv = (const float*)d_in[3];
    float* out = (float*)d_out;
    const int B = in_sizes[0] / (TL * CL);   // 4096

    if (ws_size >= (size_t)WS_ELEMS * sizeof(u16)) {
        prepack_w<<<(WS_ELEMS + 255) / 256, 256, 0, stream>>>(Wk, Wq, Wv, (u16*)d_ws);
        head_mfma<1><<<dim3(B), dim3(256), LDS_BYTES, stream>>>(x, Wk, Wq, Wv, (const u16*)d_ws, out);
    } else {
        head_mfma<0><<<dim3(B), dim3(256), LDS_BYTES, stream>>>(x, Wk, Wq, Wv, nullptr, out);
    }
}